// Round 6
// baseline (339.663 us; speedup 1.0000x reference)
//
#include <hip/hip_runtime.h>
#include <hip/hip_bf16.h>
#include <cmath>

#define Bn 4
#define Hn 32
#define Qn 64
#define Dn 128
#define Tn 4096
#define Rn 128
#define NTHREADS 512
#define SCALE_QK 0.08838834764831845f
#define NUNITS 66      // 64 quantized KV tiles of 64 + 2 residual tiles

typedef __attribute__((ext_vector_type(8))) short short8;
typedef __attribute__((ext_vector_type(4))) float f32x4;

__device__ __forceinline__ unsigned pk2(float a, float b) {
    __hip_bfloat162 h = __float22bfloat162_rn(make_float2(a, b));
    unsigned u; __builtin_memcpy(&u, &h, 4); return u;
}
__device__ __forceinline__ short8 pack8(float4 f0, float4 f1) {
    unsigned u[4] = { pk2(f0.x,f0.y), pk2(f0.z,f0.w), pk2(f1.x,f1.y), pk2(f1.z,f1.w) };
    short8 s; __builtin_memcpy(&s, u, 16); return s;
}
__device__ __forceinline__ unsigned dq2(unsigned c0, unsigned c1, int j,
                                        float s0, float m0, float s1, float m1) {
    float v0 = (float)((c0 >> (4*j)) & 15u) * s0 + m0;
    float v1 = (float)((c1 >> (4*j)) & 15u) * s1 + m1;
    return pk2(v0, v1);
}

// LDS arena: exactly 40960 B -> 4 blocks/CU (160 KiB).
//   KpB = SMEM          : K tile [t=64][d=128] bf16, 256B rows, key ((t&7)^((t>>3)&7))<<4
//   VtB = SMEM + 16384  : V^T    [d=128][t=64] bf16, 128B rows, key ((d&7)^((d>>3)&7))<<4
//   PlB = SMEM + 32768  : P      [q=64][t=64]  bf16, 128B rows, key ((q&7)^((q>>3)&7))<<4
// epilogue overlay: SMEM[0..32768) = O-scratch f32[64][128]; SMEM+32768 = mB[64], +33024 = lB[64]
template<int NS>
__global__ __launch_bounds__(NTHREADS, 8)
void kivi_attn(const float* __restrict__ qry,
               const int*   __restrict__ kcode,
               const float* __restrict__ kscale,
               const float* __restrict__ kmn,
               const float* __restrict__ kfull,
               const int*   __restrict__ vcode,
               const float* __restrict__ vscale,
               const float* __restrict__ vmn,
               const float* __restrict__ vfull,
               float* __restrict__ out,
               float* __restrict__ ws)
{
    __shared__ __align__(16) char SMEM[40960];
    char* KpB = SMEM;
    char* VtB = SMEM + 16384;
    char* PlB = SMEM + 32768;

    const int tid = threadIdx.x;
    const int bh  = blockIdx.x / NS;
    const int sp  = blockIdx.x % NS;
    const int pb  = bh * NS + sp;
    const int ulo = (sp * NUNITS) / NS;
    const int uhi = ((sp + 1) * NUNITS) / NS;

    const int*   kc  = kcode  + (size_t)bh * (Dn * (Tn / 8));
    const float* ksc = kscale + (size_t)bh * (Dn * (Tn / 32));
    const float* kmm = kmn    + (size_t)bh * (Dn * (Tn / 32));
    const float* kf  = kfull  + (size_t)bh * (Rn * Dn);
    const int*   vc  = vcode  + (size_t)bh * (Tn * (Dn / 8));
    const float* vsc = vscale + (size_t)bh * (Tn * (Dn / 32));
    const float* vmm = vmn    + (size_t)bh * (Tn * (Dn / 32));
    const float* vf  = vfull  + (size_t)bh * (Rn * Dn);

    const int w    = tid >> 6;        // wave 0..7
    const int lane = tid & 63;
    const int qg   = w & 3;           // q-group (16 rows each)
    const int th   = w >> 2;          // t-half 0/1
    const int g    = lane >> 4;       // MFMA group
    const int r    = lane & 15;       // MFMA row/col lane

    const int ktw = tid & 7,  kdp = tid >> 3;    // K: t-octet, d-pair
    const int vwd = tid & 15, vtp = tid >> 4;    // V: d-octet-word, t-pair

    // ---- Q B-fragments (scale baked in) ----
    short8 qb[4];
    {
        const float* qrow = qry + ((size_t)bh * Qn + (16 * qg + r)) * Dn;
        #pragma unroll
        for (int m = 0; m < 4; ++m) {
            float4 f0 = *(const float4*)(qrow + m * 32 + 8 * g);
            float4 f1 = *(const float4*)(qrow + m * 32 + 8 * g + 4);
            f0.x *= SCALE_QK; f0.y *= SCALE_QK; f0.z *= SCALE_QK; f0.w *= SCALE_QK;
            f1.x *= SCALE_QK; f1.y *= SCALE_QK; f1.z *= SCALE_QK; f1.w *= SCALE_QK;
            qb[m] = pack8(f0, f1);
        }
    }

    f32x4 o[8];
    #pragma unroll
    for (int nd = 0; nd < 8; ++nd) o[nd] = (f32x4){0.f, 0.f, 0.f, 0.f};
    float m_run = -INFINITY, l_run = 0.f;

    // ---- running prefetch pointers ----
    const int*   kpp  = kc  + (size_t)(2 * kdp) * (Tn / 8)  + ulo * 8 + ktw;
    const float* kscp = ksc + (size_t)(2 * kdp) * (Tn / 32) + ulo * 2 + (ktw >> 2);
    const float* kmmp = kmm + (size_t)(2 * kdp) * (Tn / 32) + ulo * 2 + (ktw >> 2);
    const int*   vcp  = vc  + ((size_t)ulo * 64 + 2 * vtp) * (Dn / 8)  + vwd;
    const float* vscp = vsc + ((size_t)ulo * 64 + 2 * vtp) * (Dn / 32) + (vwd >> 2);
    const float* vmmp = vmm + ((size_t)ulo * 64 + 2 * vtp) * (Dn / 32) + (vwd >> 2);

    int kc0, kc1, vc0, vc1;
    float ksc0, kmn0, ksc1, kmn1, vsc0, vmn0, vsc1, vmn1;
    auto pf = [&]() {
        kc0 = kpp[0]; kc1 = kpp[Tn / 8];
        ksc0 = kscp[0]; ksc1 = kscp[Tn / 32];
        kmn0 = kmmp[0]; kmn1 = kmmp[Tn / 32];
        vc0 = vcp[0]; vc1 = vcp[Dn / 8];
        vsc0 = vscp[0]; vsc1 = vscp[Dn / 32];
        vmn0 = vmmp[0]; vmn1 = vmmp[Dn / 32];
        kpp += 8; kscp += 2; kmmp += 2;
        vcp += 64 * (Dn / 8); vscp += 64 * (Dn / 32); vmmp += 64 * (Dn / 32);
    };
    pf();   // unit ulo (always quantized since ulo < 64 for NS<=8)

    const int q    = 16 * qg + r;
    const int pkey = (((q & 7) ^ ((q >> 3) & 7)) << 4);

    for (int u = ulo; u < uhi; ++u) {
        __syncthreads();   // B1: all consumers of previous tile done

        if (u < 64) {
            {   // K dequant: rows (d=2kdp, 2kdp+1), t = 8*ktw + j
                unsigned c0 = (unsigned)kc0, c1 = (unsigned)kc1;
                #pragma unroll
                for (int j = 0; j < 8; ++j) {
                    int t = 8 * ktw + j;
                    int key = (j ^ ktw) << 4;
                    *(unsigned*)(KpB + (((t << 8) + 4 * kdp) ^ key)) =
                        dq2(c0, c1, j, ksc0, kmn0, ksc1, kmn1);
                }
            }
            {   // V dequant: rows (t=2vtp, 2vtp+1), d = 8*vwd + i
                unsigned c0 = (unsigned)vc0, c1 = (unsigned)vc1;
                #pragma unroll
                for (int i = 0; i < 8; ++i) {
                    int d = 8 * vwd + i;
                    int key = (i ^ (vwd & 7)) << 4;
                    *(unsigned*)(VtB + (((d << 7) + 4 * vtp) ^ key)) =
                        dq2(c0, c1, i, vsc0, vmn0, vsc1, vmn1);
                }
            }
        } else {
            int rt = u - 64;
            {   // K residual fp32
                int t = tid & 63, dh = tid >> 6;
                const float* kr = kf + (size_t)(rt * 64 + t) * Dn + dh * 16;
                int key = ((t & 7) ^ ((t >> 3) & 7)) << 4;
                #pragma unroll
                for (int s = 0; s < 2; ++s) {
                    float4 f0 = *(const float4*)(kr + s * 8);
                    float4 f1 = *(const float4*)(kr + s * 8 + 4);
                    *(short8*)(KpB + (((t << 8) + dh * 32 + s * 16) ^ key)) = pack8(f0, f1);
                }
            }
            {   // V residual fp32 (transposed gather)
                int d = tid & 127, t4 = tid >> 7;
                const float* vr = vf + (size_t)(rt * 64 + t4 * 16) * Dn + d;
                int key = ((d & 7) ^ ((d >> 3) & 7)) << 4;
                #pragma unroll
                for (int s = 0; s < 2; ++s) {
                    float4 f0, f1;
                    f0.x = vr[(size_t)(s * 8 + 0) * Dn]; f0.y = vr[(size_t)(s * 8 + 1) * Dn];
                    f0.z = vr[(size_t)(s * 8 + 2) * Dn]; f0.w = vr[(size_t)(s * 8 + 3) * Dn];
                    f1.x = vr[(size_t)(s * 8 + 4) * Dn]; f1.y = vr[(size_t)(s * 8 + 5) * Dn];
                    f1.z = vr[(size_t)(s * 8 + 6) * Dn]; f1.w = vr[(size_t)(s * 8 + 7) * Dn];
                    *(short8*)(VtB + (((d << 7) + t4 * 32 + s * 16) ^ key)) = pack8(f0, f1);
                }
            }
        }
        __syncthreads();   // B2: tile staged

        // ---- issue next unit's global loads (drained under QK+softmax+PV) ----
        if (u + 1 < uhi && u + 1 < 64) pf();

        // ---- S^T = K Q^T via swapped MFMA ----
        f32x4 s0 = {0.f,0.f,0.f,0.f}, s1 = {0.f,0.f,0.f,0.f};
        {
            int t0 = 32 * th + r, t1 = t0 + 16;
            int k0 = ((t0 & 7) ^ ((t0 >> 3) & 7)) << 4;
            int k1 = ((t1 & 7) ^ ((t1 >> 3) & 7)) << 4;
            int b0 = (t0 << 8) + (g << 4);
            int b1 = (t1 << 8) + (g << 4);
            #pragma unroll
            for (int m = 0; m < 4; ++m) {
                short8 f0 = *(const short8*)(KpB + ((b0 + (m << 6)) ^ k0));
                short8 f1 = *(const short8*)(KpB + ((b1 + (m << 6)) ^ k1));
                s0 = __builtin_amdgcn_mfma_f32_16x16x32_bf16(f0, qb[m], s0, 0, 0, 0);
                s1 = __builtin_amdgcn_mfma_f32_16x16x32_bf16(f1, qb[m], s1, 0, 0, 0);
            }
        }

        // ---- causal mask (residual tiles only) ----
        if (u >= 64) {
            int rbase = (u - 64) * 64 + 32 * th + 4 * g;
            #pragma unroll
            for (int reg = 0; reg < 4; ++reg) {
                if (rbase + reg      > 64 + q) s0[reg] = -1e30f;
                if (rbase + 16 + reg > 64 + q) s1[reg] = -1e30f;
            }
        }

        // ---- in-register online softmax over this half's 32 t ----
        float alpha;
        {
            float mx = fmaxf(fmaxf(fmaxf(s0[0], s0[1]), fmaxf(s0[2], s0[3])),
                             fmaxf(fmaxf(s1[0], s1[1]), fmaxf(s1[2], s1[3])));
            mx = fmaxf(mx, __shfl_xor(mx, 16));
            mx = fmaxf(mx, __shfl_xor(mx, 32));
            float mnew = fmaxf(m_run, mx);
            float p0[4], p1[4];
            #pragma unroll
            for (int reg = 0; reg < 4; ++reg) {
                p0[reg] = __expf(s0[reg] - mnew);
                p1[reg] = __expf(s1[reg] - mnew);
            }
            float sum = ((p0[0] + p0[1]) + (p0[2] + p0[3]))
                      + ((p1[0] + p1[1]) + (p1[2] + p1[3]));
            sum += __shfl_xor(sum, 16);
            sum += __shfl_xor(sum, 32);
            alpha = __expf(m_run - mnew);
            l_run = l_run * alpha + sum;
            m_run = mnew;
            int pb0 = (q << 7) + 64 * th + 8 * g;
            *(unsigned*)(PlB + ((pb0     ) ^ pkey)) = pk2(p0[0], p0[1]);
            *(unsigned*)(PlB + ((pb0 +  4) ^ pkey)) = pk2(p0[2], p0[3]);
            *(unsigned*)(PlB + ((pb0 + 32) ^ pkey)) = pk2(p1[0], p1[1]);
            *(unsigned*)(PlB + ((pb0 + 36) ^ pkey)) = pk2(p1[2], p1[3]);
        }
        // NO barrier: P + alpha are wave-local (lgkmcnt ordering suffices)

        // ---- O = O*alpha + P V (this half's K=32 t-slice) ----
        {
            #pragma unroll
            for (int reg = 0; reg < 4; ++reg) {
                float av = __shfl(alpha, 4 * g + reg, 16);
                #pragma unroll
                for (int nd = 0; nd < 8; ++nd) o[nd][reg] *= av;
            }
            short8 pa = *(const short8*)(PlB + (((q << 7) + 64 * th + 16 * g) ^ pkey));
            #pragma unroll
            for (int nd = 0; nd < 8; ++nd) {
                int d = r + 16 * nd;
                int vkey = ((d & 7) ^ ((d >> 3) & 7)) << 4;
                short8 vb = *(const short8*)(VtB + (((d << 7) + 64 * th + 16 * g) ^ vkey));
                o[nd] = __builtin_amdgcn_mfma_f32_16x16x32_bf16(pa, vb, o[nd], 0, 0, 0);
            }
        }
    }

    // ---- epilogue: merge t-halves in LDS overlay, write partial/final O ----
    __syncthreads();   // all PV reads of VtB done; arena reusable
    {
        float* Osc = (float*)SMEM;                 // [64][128] f32 = 32 KB
        float* mB  = (float*)(SMEM + 32768);       // [64]
        float* lB  = (float*)(SMEM + 32768 + 256); // [64]
        if (th == 1) {
            #pragma unroll
            for (int reg = 0; reg < 4; ++reg) {
                int qrow = 16 * qg + 4 * g + reg;
                #pragma unroll
                for (int nd = 0; nd < 8; ++nd)
                    Osc[qrow * 128 + r + 16 * nd] = o[nd][reg];
            }
            if (g == 0) { mB[16 * qg + r] = m_run; lB[16 * qg + r] = l_run; }
        }
        __syncthreads();
        if (th == 0) {
            float* wsO = ws;
            float* wsM = ws + (size_t)128 * NS * 8192;
            float* wsL = wsM + (size_t)128 * NS * 64;
            #pragma unroll
            for (int reg = 0; reg < 4; ++reg) {
                int qrow = 16 * qg + 4 * g + reg;
                float m1v = __shfl(m_run, 4 * g + reg, 16);
                float l1v = __shfl(l_run, 4 * g + reg, 16);
                float m2v = mB[qrow], l2v = lB[qrow];
                float M  = fmaxf(m1v, m2v);
                float w1 = __expf(m1v - M), w2 = __expf(m2v - M);
                float lt = l1v * w1 + l2v * w2;
                if (NS == 1) {
                    float inv = 1.0f / lt;
                    #pragma unroll
                    for (int nd = 0; nd < 8; ++nd)
                        out[(size_t)bh * 8192 + qrow * 128 + r + 16 * nd] =
                            (o[nd][reg] * w1 + Osc[qrow * 128 + r + 16 * nd] * w2) * inv;
                } else {
                    float* Op = wsO + (size_t)pb * 8192;
                    #pragma unroll
                    for (int nd = 0; nd < 8; ++nd)
                        Op[qrow * 128 + r + 16 * nd] =
                            o[nd][reg] * w1 + Osc[qrow * 128 + r + 16 * nd] * w2;
                    if (r == 0) { wsM[pb * 64 + qrow] = M; wsL[pb * 64 + qrow] = lt; }
                }
            }
        }
    }
}

template<int NS>
__global__ __launch_bounds__(256, 1)
void kivi_combine(const float* __restrict__ ws, float* __restrict__ out)
{
    const int bh  = blockIdx.x;
    const int tid = threadIdx.x;
    const int q   = tid >> 2;
    const int dq  = (tid & 3) << 5;
    const float* wsO = ws;
    const float* wsM = ws + (size_t)128 * NS * 8192;
    const float* wsL = wsM + (size_t)128 * NS * 64;

    float mv[NS];
    float M = -INFINITY;
    #pragma unroll
    for (int sp = 0; sp < NS; ++sp) {
        mv[sp] = wsM[(bh * NS + sp) * 64 + q];
        M = fmaxf(M, mv[sp]);
    }
    float lt = 0.f;
    #pragma unroll
    for (int sp = 0; sp < NS; ++sp) {
        mv[sp] = __expf(mv[sp] - M);
        lt += wsL[(bh * NS + sp) * 64 + q] * mv[sp];
    }
    float inv = 1.0f / lt;
    float4 acc[8];
    #pragma unroll
    for (int i = 0; i < 8; ++i) acc[i] = make_float4(0.f, 0.f, 0.f, 0.f);
    #pragma unroll
    for (int sp = 0; sp < NS; ++sp) {
        const float* Op = wsO + ((size_t)(bh * NS + sp)) * 8192 + q * 128 + dq;
        float wgt = mv[sp];
        #pragma unroll
        for (int i = 0; i < 8; ++i) {
            float4 f = *(const float4*)(Op + 4 * i);
            acc[i].x += f.x * wgt; acc[i].y += f.y * wgt;
            acc[i].z += f.z * wgt; acc[i].w += f.w * wgt;
        }
    }
    float* op = out + (size_t)bh * 8192 + q * 128 + dq;
    #pragma unroll
    for (int i = 0; i < 8; ++i) {
        float4 f = make_float4(acc[i].x * inv, acc[i].y * inv, acc[i].z * inv, acc[i].w * inv);
        *(float4*)(op + 4 * i) = f;
    }
}

extern "C" void kernel_launch(void* const* d_in, const int* in_sizes, int n_in,
                              void* d_out, int out_size, void* d_ws, size_t ws_size,
                              hipStream_t stream) {
    const float* qry    = (const float*)d_in[0];
    const int*   kcode  = (const int*)  d_in[1];
    const float* kscale = (const float*)d_in[2];
    const float* kmn    = (const float*)d_in[3];
    const float* kfull  = (const float*)d_in[4];
    const int*   vcode  = (const int*)  d_in[5];
    const float* vscale = (const float*)d_in[6];
    const float* vmn    = (const float*)d_in[7];
    const float* vfull  = (const float*)d_in[8];
    float* out = (float*)d_out;
    float* ws  = (float*)d_ws;

    const size_t needPerNS = ((size_t)128 * 8192 + 2 * 128 * 64) * sizeof(float);
    if (ws_size >= 8 * needPerNS) {
        kivi_attn<8><<<dim3(Bn * Hn * 8), dim3(NTHREADS), 0, stream>>>(
            qry, kcode, kscale, kmn, kfull, vcode, vscale, vmn, vfull, out, ws);
        kivi_combine<8><<<dim3(Bn * Hn), dim3(256), 0, stream>>>(ws, out);
    } else if (ws_size >= 4 * needPerNS) {
        kivi_attn<4><<<dim3(Bn * Hn * 4), dim3(NTHREADS), 0, stream>>>(
            qry, kcode, kscale, kmn, kfull, vcode, vscale, vmn, vfull, out, ws);
        kivi_combine<4><<<dim3(Bn * Hn), dim3(256), 0, stream>>>(ws, out);
    } else if (ws_size >= 2 * needPerNS) {
        kivi_attn<2><<<dim3(Bn * Hn * 2), dim3(NTHREADS), 0, stream>>>(
            qry, kcode, kscale, kmn, kfull, vcode, vscale, vmn, vfull, out, ws);
        kivi_combine<2><<<dim3(Bn * Hn), dim3(256), 0, stream>>>(ws, out);
    } else {
        kivi_attn<1><<<dim3(Bn * Hn), dim3(NTHREADS), 0, stream>>>(
            qry, kcode, kscale, kmn, kfull, vcode, vscale, vmn, vfull, out, ws);
    }
}

// Round 7
// 147.959 us; speedup vs baseline: 2.2957x; 2.2957x over previous
//
#include <hip/hip_runtime.h>
#include <hip/hip_bf16.h>
#include <cmath>

#define Bn 4
#define Hn 32
#define Qn 64
#define Dn 128
#define Tn 4096
#define Rn 128
#define NTHREADS 512
#define SCALE_QK 0.08838834764831845f
#define NUNITS 66      // 64 quantized KV tiles of 64 + 2 residual tiles

typedef __attribute__((ext_vector_type(8))) short short8;
typedef __attribute__((ext_vector_type(4))) float f32x4;

__device__ __forceinline__ unsigned pk2(float a, float b) {
    __hip_bfloat162 h = __float22bfloat162_rn(make_float2(a, b));
    unsigned u; __builtin_memcpy(&u, &h, 4); return u;
}
__device__ __forceinline__ short8 pack8(float4 f0, float4 f1) {
    unsigned u[4] = { pk2(f0.x,f0.y), pk2(f0.z,f0.w), pk2(f1.x,f1.y), pk2(f1.z,f1.w) };
    short8 s; __builtin_memcpy(&s, u, 16); return s;
}
__device__ __forceinline__ unsigned dq2(unsigned c0, unsigned c1, int j,
                                        float s0, float m0, float s1, float m1) {
    float v0 = (float)((c0 >> (4*j)) & 15u) * s0 + m0;
    float v1 = (float)((c1 >> (4*j)) & 15u) * s1 + m1;
    return pk2(v0, v1);
}

// LDS arena: exactly 40960 B -> 4 blocks/CU (160 KiB).
//   KpB = SMEM          : K tile [t=64][d=128] bf16, 256B rows, key ((t&7)^((t>>3)&7))<<4
//   VtB = SMEM + 16384  : V^T    [d=128][t=64] bf16, 128B rows, key ((d&7)^((d>>3)&7))<<4
//   PlB = SMEM + 32768  : P      [q=64][t=64]  bf16, 128B rows, key ((q&7)^((q>>3)&7))<<4
// epilogue overlay: SMEM[0..32768) = O-scratch f32[64][128]; +32768 = mB[64], +33024 = lB[64]
// NOTE: __launch_bounds__(512,4) — NOT 8: w=8 caps VGPR too low and spills
// the f32x4 o[8] accumulator to scratch (R6: VGPR 32, WRITE_SIZE 426 MB, 2.4x slower).
template<int NS>
__global__ __launch_bounds__(NTHREADS, 4)
void kivi_attn(const float* __restrict__ qry,
               const int*   __restrict__ kcode,
               const float* __restrict__ kscale,
               const float* __restrict__ kmn,
               const float* __restrict__ kfull,
               const int*   __restrict__ vcode,
               const float* __restrict__ vscale,
               const float* __restrict__ vmn,
               const float* __restrict__ vfull,
               float* __restrict__ out,
               float* __restrict__ ws)
{
    __shared__ __align__(16) char SMEM[40960];
    char* KpB = SMEM;
    char* VtB = SMEM + 16384;
    char* PlB = SMEM + 32768;

    const int tid = threadIdx.x;
    const int bh  = blockIdx.x / NS;
    const int sp  = blockIdx.x % NS;
    const int pb  = bh * NS + sp;
    const int ulo = (sp * NUNITS) / NS;
    const int uhi = ((sp + 1) * NUNITS) / NS;

    const int*   kc  = kcode  + (size_t)bh * (Dn * (Tn / 8));
    const float* ksc = kscale + (size_t)bh * (Dn * (Tn / 32));
    const float* kmm = kmn    + (size_t)bh * (Dn * (Tn / 32));
    const float* kf  = kfull  + (size_t)bh * (Rn * Dn);
    const int*   vc  = vcode  + (size_t)bh * (Tn * (Dn / 8));
    const float* vsc = vscale + (size_t)bh * (Tn * (Dn / 32));
    const float* vmm = vmn    + (size_t)bh * (Tn * (Dn / 32));
    const float* vf  = vfull  + (size_t)bh * (Rn * Dn);

    const int w    = tid >> 6;        // wave 0..7
    const int lane = tid & 63;
    const int qg   = w & 3;           // q-group (16 rows each)
    const int th   = w >> 2;          // t-half 0/1
    const int g    = lane >> 4;       // MFMA group
    const int r    = lane & 15;       // MFMA row/col lane

    const int ktw = tid & 7,  kdp = tid >> 3;    // K: t-octet, d-pair
    const int vwd = tid & 15, vtp = tid >> 4;    // V: d-octet-word, t-pair

    // ---- Q B-fragments (scale baked in) ----
    short8 qb[4];
    {
        const float* qrow = qry + ((size_t)bh * Qn + (16 * qg + r)) * Dn;
        #pragma unroll
        for (int m = 0; m < 4; ++m) {
            float4 f0 = *(const float4*)(qrow + m * 32 + 8 * g);
            float4 f1 = *(const float4*)(qrow + m * 32 + 8 * g + 4);
            f0.x *= SCALE_QK; f0.y *= SCALE_QK; f0.z *= SCALE_QK; f0.w *= SCALE_QK;
            f1.x *= SCALE_QK; f1.y *= SCALE_QK; f1.z *= SCALE_QK; f1.w *= SCALE_QK;
            qb[m] = pack8(f0, f1);
        }
    }

    f32x4 o[8];
    #pragma unroll
    for (int nd = 0; nd < 8; ++nd) o[nd] = (f32x4){0.f, 0.f, 0.f, 0.f};
    float m_run = -INFINITY, l_run = 0.f;

    // ---- running prefetch pointers ----
    const int*   kpp  = kc  + (size_t)(2 * kdp) * (Tn / 8)  + ulo * 8 + ktw;
    const float* kscp = ksc + (size_t)(2 * kdp) * (Tn / 32) + ulo * 2 + (ktw >> 2);
    const float* kmmp = kmm + (size_t)(2 * kdp) * (Tn / 32) + ulo * 2 + (ktw >> 2);
    const int*   vcp  = vc  + ((size_t)ulo * 64 + 2 * vtp) * (Dn / 8)  + vwd;
    const float* vscp = vsc + ((size_t)ulo * 64 + 2 * vtp) * (Dn / 32) + (vwd >> 2);
    const float* vmmp = vmm + ((size_t)ulo * 64 + 2 * vtp) * (Dn / 32) + (vwd >> 2);

    int kc0, kc1, vc0, vc1;
    float ksc0, kmn0, ksc1, kmn1, vsc0, vmn0, vsc1, vmn1;
    auto pf = [&]() {
        kc0 = kpp[0]; kc1 = kpp[Tn / 8];
        ksc0 = kscp[0]; ksc1 = kscp[Tn / 32];
        kmn0 = kmmp[0]; kmn1 = kmmp[Tn / 32];
        vc0 = vcp[0]; vc1 = vcp[Dn / 8];
        vsc0 = vscp[0]; vsc1 = vscp[Dn / 32];
        vmn0 = vmmp[0]; vmn1 = vmmp[Dn / 32];
        kpp += 8; kscp += 2; kmmp += 2;
        vcp += 64 * (Dn / 8); vscp += 64 * (Dn / 32); vmmp += 64 * (Dn / 32);
    };
    pf();   // unit ulo (always quantized since ulo < 64 for NS<=8)

    const int q    = 16 * qg + r;
    const int pkey = (((q & 7) ^ ((q >> 3) & 7)) << 4);

    for (int u = ulo; u < uhi; ++u) {
        __syncthreads();   // B1: all consumers of previous tile done

        if (u < 64) {
            {   // K dequant: rows (d=2kdp, 2kdp+1), t = 8*ktw + j
                unsigned c0 = (unsigned)kc0, c1 = (unsigned)kc1;
                #pragma unroll
                for (int j = 0; j < 8; ++j) {
                    int t = 8 * ktw + j;
                    int key = (j ^ ktw) << 4;
                    *(unsigned*)(KpB + (((t << 8) + 4 * kdp) ^ key)) =
                        dq2(c0, c1, j, ksc0, kmn0, ksc1, kmn1);
                }
            }
            {   // V dequant: rows (t=2vtp, 2vtp+1), d = 8*vwd + i
                unsigned c0 = (unsigned)vc0, c1 = (unsigned)vc1;
                #pragma unroll
                for (int i = 0; i < 8; ++i) {
                    int d = 8 * vwd + i;
                    int key = (i ^ (vwd & 7)) << 4;
                    *(unsigned*)(VtB + (((d << 7) + 4 * vtp) ^ key)) =
                        dq2(c0, c1, i, vsc0, vmn0, vsc1, vmn1);
                }
            }
        } else {
            int rt = u - 64;
            {   // K residual fp32
                int t = tid & 63, dh = tid >> 6;
                const float* kr = kf + (size_t)(rt * 64 + t) * Dn + dh * 16;
                int key = ((t & 7) ^ ((t >> 3) & 7)) << 4;
                #pragma unroll
                for (int s = 0; s < 2; ++s) {
                    float4 f0 = *(const float4*)(kr + s * 8);
                    float4 f1 = *(const float4*)(kr + s * 8 + 4);
                    *(short8*)(KpB + (((t << 8) + dh * 32 + s * 16) ^ key)) = pack8(f0, f1);
                }
            }
            {   // V residual fp32 (transposed gather)
                int d = tid & 127, t4 = tid >> 7;
                const float* vr = vf + (size_t)(rt * 64 + t4 * 16) * Dn + d;
                int key = ((d & 7) ^ ((d >> 3) & 7)) << 4;
                #pragma unroll
                for (int s = 0; s < 2; ++s) {
                    float4 f0, f1;
                    f0.x = vr[(size_t)(s * 8 + 0) * Dn]; f0.y = vr[(size_t)(s * 8 + 1) * Dn];
                    f0.z = vr[(size_t)(s * 8 + 2) * Dn]; f0.w = vr[(size_t)(s * 8 + 3) * Dn];
                    f1.x = vr[(size_t)(s * 8 + 4) * Dn]; f1.y = vr[(size_t)(s * 8 + 5) * Dn];
                    f1.z = vr[(size_t)(s * 8 + 6) * Dn]; f1.w = vr[(size_t)(s * 8 + 7) * Dn];
                    *(short8*)(VtB + (((d << 7) + t4 * 32 + s * 16) ^ key)) = pack8(f0, f1);
                }
            }
        }
        __syncthreads();   // B2: tile staged

        // ---- issue next unit's global loads (drained under QK+softmax+PV) ----
        if (u + 1 < uhi && u + 1 < 64) pf();

        // ---- S^T = K Q^T via swapped MFMA ----
        f32x4 s0 = {0.f,0.f,0.f,0.f}, s1 = {0.f,0.f,0.f,0.f};
        {
            int t0 = 32 * th + r, t1 = t0 + 16;
            int k0 = ((t0 & 7) ^ ((t0 >> 3) & 7)) << 4;
            int k1 = ((t1 & 7) ^ ((t1 >> 3) & 7)) << 4;
            int b0 = (t0 << 8) + (g << 4);
            int b1 = (t1 << 8) + (g << 4);
            #pragma unroll
            for (int m = 0; m < 4; ++m) {
                short8 f0 = *(const short8*)(KpB + ((b0 + (m << 6)) ^ k0));
                short8 f1 = *(const short8*)(KpB + ((b1 + (m << 6)) ^ k1));
                s0 = __builtin_amdgcn_mfma_f32_16x16x32_bf16(f0, qb[m], s0, 0, 0, 0);
                s1 = __builtin_amdgcn_mfma_f32_16x16x32_bf16(f1, qb[m], s1, 0, 0, 0);
            }
        }

        // ---- causal mask (residual tiles only) ----
        if (u >= 64) {
            int rbase = (u - 64) * 64 + 32 * th + 4 * g;
            #pragma unroll
            for (int reg = 0; reg < 4; ++reg) {
                if (rbase + reg      > 64 + q) s0[reg] = -1e30f;
                if (rbase + 16 + reg > 64 + q) s1[reg] = -1e30f;
            }
        }

        // ---- in-register online softmax over this half's 32 t ----
        float alpha;
        {
            float mx = fmaxf(fmaxf(fmaxf(s0[0], s0[1]), fmaxf(s0[2], s0[3])),
                             fmaxf(fmaxf(s1[0], s1[1]), fmaxf(s1[2], s1[3])));
            mx = fmaxf(mx, __shfl_xor(mx, 16));
            mx = fmaxf(mx, __shfl_xor(mx, 32));
            float mnew = fmaxf(m_run, mx);
            float p0[4], p1[4];
            #pragma unroll
            for (int reg = 0; reg < 4; ++reg) {
                p0[reg] = __expf(s0[reg] - mnew);
                p1[reg] = __expf(s1[reg] - mnew);
            }
            float sum = ((p0[0] + p0[1]) + (p0[2] + p0[3]))
                      + ((p1[0] + p1[1]) + (p1[2] + p1[3]));
            sum += __shfl_xor(sum, 16);
            sum += __shfl_xor(sum, 32);
            alpha = __expf(m_run - mnew);
            l_run = l_run * alpha + sum;
            m_run = mnew;
            int pb0 = (q << 7) + 64 * th + 8 * g;
            *(unsigned*)(PlB + ((pb0     ) ^ pkey)) = pk2(p0[0], p0[1]);
            *(unsigned*)(PlB + ((pb0 +  4) ^ pkey)) = pk2(p0[2], p0[3]);
            *(unsigned*)(PlB + ((pb0 + 32) ^ pkey)) = pk2(p1[0], p1[1]);
            *(unsigned*)(PlB + ((pb0 + 36) ^ pkey)) = pk2(p1[2], p1[3]);
        }
        // NO barrier: P + alpha are wave-local (lgkmcnt ordering suffices)

        // ---- O = O*alpha + P V (this half's K=32 t-slice) ----
        {
            #pragma unroll
            for (int reg = 0; reg < 4; ++reg) {
                float av = __shfl(alpha, 4 * g + reg, 16);
                #pragma unroll
                for (int nd = 0; nd < 8; ++nd) o[nd][reg] *= av;
            }
            short8 pa = *(const short8*)(PlB + (((q << 7) + 64 * th + 16 * g) ^ pkey));
            #pragma unroll
            for (int nd = 0; nd < 8; ++nd) {
                int d = r + 16 * nd;
                int vkey = ((d & 7) ^ ((d >> 3) & 7)) << 4;
                short8 vb = *(const short8*)(VtB + (((d << 7) + 64 * th + 16 * g) ^ vkey));
                o[nd] = __builtin_amdgcn_mfma_f32_16x16x32_bf16(pa, vb, o[nd], 0, 0, 0);
            }
        }
    }

    // ---- epilogue: merge t-halves in LDS overlay, write partial/final O ----
    __syncthreads();   // all PV reads of VtB done; arena reusable
    {
        float* Osc = (float*)SMEM;                 // [64][128] f32 = 32 KB
        float* mB  = (float*)(SMEM + 32768);       // [64]
        float* lB  = (float*)(SMEM + 32768 + 256); // [64]
        if (th == 1) {
            #pragma unroll
            for (int reg = 0; reg < 4; ++reg) {
                int qrow = 16 * qg + 4 * g + reg;
                #pragma unroll
                for (int nd = 0; nd < 8; ++nd)
                    Osc[qrow * 128 + r + 16 * nd] = o[nd][reg];
            }
            if (g == 0) { mB[16 * qg + r] = m_run; lB[16 * qg + r] = l_run; }
        }
        __syncthreads();
        if (th == 0) {
            float* wsO = ws;
            float* wsM = ws + (size_t)128 * NS * 8192;
            float* wsL = wsM + (size_t)128 * NS * 64;
            #pragma unroll
            for (int reg = 0; reg < 4; ++reg) {
                int qrow = 16 * qg + 4 * g + reg;
                float m1v = __shfl(m_run, 4 * g + reg, 16);
                float l1v = __shfl(l_run, 4 * g + reg, 16);
                float m2v = mB[qrow], l2v = lB[qrow];
                float M  = fmaxf(m1v, m2v);
                float w1 = __expf(m1v - M), w2 = __expf(m2v - M);
                float lt = l1v * w1 + l2v * w2;
                if (NS == 1) {
                    float inv = 1.0f / lt;
                    #pragma unroll
                    for (int nd = 0; nd < 8; ++nd)
                        out[(size_t)bh * 8192 + qrow * 128 + r + 16 * nd] =
                            (o[nd][reg] * w1 + Osc[qrow * 128 + r + 16 * nd] * w2) * inv;
                } else {
                    float* Op = wsO + (size_t)pb * 8192;
                    #pragma unroll
                    for (int nd = 0; nd < 8; ++nd)
                        Op[qrow * 128 + r + 16 * nd] =
                            o[nd][reg] * w1 + Osc[qrow * 128 + r + 16 * nd] * w2;
                    if (r == 0) { wsM[pb * 64 + qrow] = M; wsL[pb * 64 + qrow] = lt; }
                }
            }
        }
    }
}

template<int NS>
__global__ __launch_bounds__(256, 1)
void kivi_combine(const float* __restrict__ ws, float* __restrict__ out)
{
    const int bh  = blockIdx.x;
    const int tid = threadIdx.x;
    const int q   = tid >> 2;
    const int dq  = (tid & 3) << 5;
    const float* wsO = ws;
    const float* wsM = ws + (size_t)128 * NS * 8192;
    const float* wsL = wsM + (size_t)128 * NS * 64;

    float mv[NS];
    float M = -INFINITY;
    #pragma unroll
    for (int sp = 0; sp < NS; ++sp) {
        mv[sp] = wsM[(bh * NS + sp) * 64 + q];
        M = fmaxf(M, mv[sp]);
    }
    float lt = 0.f;
    #pragma unroll
    for (int sp = 0; sp < NS; ++sp) {
        mv[sp] = __expf(mv[sp] - M);
        lt += wsL[(bh * NS + sp) * 64 + q] * mv[sp];
    }
    float inv = 1.0f / lt;
    float4 acc[8];
    #pragma unroll
    for (int i = 0; i < 8; ++i) acc[i] = make_float4(0.f, 0.f, 0.f, 0.f);
    #pragma unroll
    for (int sp = 0; sp < NS; ++sp) {
        const float* Op = wsO + ((size_t)(bh * NS + sp)) * 8192 + q * 128 + dq;
        float wgt = mv[sp];
        #pragma unroll
        for (int i = 0; i < 8; ++i) {
            float4 f = *(const float4*)(Op + 4 * i);
            acc[i].x += f.x * wgt; acc[i].y += f.y * wgt;
            acc[i].z += f.z * wgt; acc[i].w += f.w * wgt;
        }
    }
    float* op = out + (size_t)bh * 8192 + q * 128 + dq;
    #pragma unroll
    for (int i = 0; i < 8; ++i) {
        float4 f = make_float4(acc[i].x * inv, acc[i].y * inv, acc[i].z * inv, acc[i].w * inv);
        *(float4*)(op + 4 * i) = f;
    }
}

extern "C" void kernel_launch(void* const* d_in, const int* in_sizes, int n_in,
                              void* d_out, int out_size, void* d_ws, size_t ws_size,
                              hipStream_t stream) {
    const float* qry    = (const float*)d_in[0];
    const int*   kcode  = (const int*)  d_in[1];
    const float* kscale = (const float*)d_in[2];
    const float* kmn    = (const float*)d_in[3];
    const float* kfull  = (const float*)d_in[4];
    const int*   vcode  = (const int*)  d_in[5];
    const float* vscale = (const float*)d_in[6];
    const float* vmn    = (const float*)d_in[7];
    const float* vfull  = (const float*)d_in[8];
    float* out = (float*)d_out;
    float* ws  = (float*)d_ws;

    const size_t needPerNS = ((size_t)128 * 8192 + 2 * 128 * 64) * sizeof(float);
    if (ws_size >= 8 * needPerNS) {
        kivi_attn<8><<<dim3(Bn * Hn * 8), dim3(NTHREADS), 0, stream>>>(
            qry, kcode, kscale, kmn, kfull, vcode, vscale, vmn, vfull, out, ws);
        kivi_combine<8><<<dim3(Bn * Hn), dim3(256), 0, stream>>>(ws, out);
    } else if (ws_size >= 4 * needPerNS) {
        kivi_attn<4><<<dim3(Bn * Hn * 4), dim3(NTHREADS), 0, stream>>>(
            qry, kcode, kscale, kmn, kfull, vcode, vscale, vmn, vfull, out, ws);
        kivi_combine<4><<<dim3(Bn * Hn), dim3(256), 0, stream>>>(ws, out);
    } else if (ws_size >= 2 * needPerNS) {
        kivi_attn<2><<<dim3(Bn * Hn * 2), dim3(NTHREADS), 0, stream>>>(
            qry, kcode, kscale, kmn, kfull, vcode, vscale, vmn, vfull, out, ws);
        kivi_combine<2><<<dim3(Bn * Hn), dim3(256), 0, stream>>>(ws, out);
    } else {
        kivi_attn<1><<<dim3(Bn * Hn), dim3(NTHREADS), 0, stream>>>(
            qry, kcode, kscale, kmn, kfull, vcode, vscale, vmn, vfull, out, ws);
    }
}

// Round 8
// 132.771 us; speedup vs baseline: 2.5583x; 1.1144x over previous
//
#include <hip/hip_runtime.h>
#include <hip/hip_bf16.h>
#include <cmath>

#define Bn 4
#define Hn 32
#define Qn 64
#define Dn 128
#define Tn 4096
#define Rn 128
#define NTHREADS 512
#define SCALE_QK 0.08838834764831845f
#define NUNITS 66      // 64 quantized KV tiles of 64 + 2 residual tiles
#define DEFER_THR 8.0f

typedef __attribute__((ext_vector_type(8))) short short8;
typedef __attribute__((ext_vector_type(4))) float f32x4;

__device__ __forceinline__ unsigned pk2(float a, float b) {
    __hip_bfloat162 h = __float22bfloat162_rn(make_float2(a, b));
    unsigned u; __builtin_memcpy(&u, &h, 4); return u;
}
__device__ __forceinline__ short8 pack8(float4 f0, float4 f1) {
    unsigned u[4] = { pk2(f0.x,f0.y), pk2(f0.z,f0.w), pk2(f1.x,f1.y), pk2(f1.z,f1.w) };
    short8 s; __builtin_memcpy(&s, u, 16); return s;
}
__device__ __forceinline__ unsigned dq2(unsigned c0, unsigned c1, int j,
                                        float s0, float m0, float s1, float m1) {
    float v0 = (float)((c0 >> (4*j)) & 15u) * s0 + m0;
    float v1 = (float)((c1 >> (4*j)) & 15u) * s1 + m1;
    return pk2(v0, v1);
}

// LDS arena 33280 B -> 4 blocks/CU (wave-capped at 32 waves anyway).
//   KpB = SMEM          : K tile [t=64][d=128] bf16, 256B rows, key ((t&7)^((t>>3)&7))<<4
//   VtB = SMEM + 16384  : V^T    [d=128][t=64] bf16, 128B rows, key ((d&7)^((d>>3)&7))<<4
// NO P buffer: permuted-QK keeps P in-lane for the swapped-PV B-fragment.
// epilogue overlay: SMEM[0..32768) = O^T scratch f32; +32768 mB[64]; +33024 lB[64]
template<int NS>
__global__ __launch_bounds__(NTHREADS, 4)
void kivi_attn(const float* __restrict__ qry,
               const int*   __restrict__ kcode,
               const float* __restrict__ kscale,
               const float* __restrict__ kmn,
               const float* __restrict__ kfull,
               const int*   __restrict__ vcode,
               const float* __restrict__ vscale,
               const float* __restrict__ vmn,
               const float* __restrict__ vfull,
               float* __restrict__ out,
               float* __restrict__ ws)
{
    __shared__ __align__(16) char SMEM[33280];
    char* KpB = SMEM;
    char* VtB = SMEM + 16384;

    const int tid = threadIdx.x;
    const int bh  = blockIdx.x / NS;
    const int sp  = blockIdx.x % NS;
    const int pb  = bh * NS + sp;
    const int ulo = (sp * NUNITS) / NS;
    const int uhi = ((sp + 1) * NUNITS) / NS;

    const int*   kc  = kcode  + (size_t)bh * (Dn * (Tn / 8));
    const float* ksc = kscale + (size_t)bh * (Dn * (Tn / 32));
    const float* kmm = kmn    + (size_t)bh * (Dn * (Tn / 32));
    const float* kf  = kfull  + (size_t)bh * (Rn * Dn);
    const int*   vc  = vcode  + (size_t)bh * (Tn * (Dn / 8));
    const float* vsc = vscale + (size_t)bh * (Tn * (Dn / 32));
    const float* vmm = vmn    + (size_t)bh * (Tn * (Dn / 32));
    const float* vf  = vfull  + (size_t)bh * (Rn * Dn);

    const int w    = tid >> 6;        // wave 0..7
    const int lane = tid & 63;
    const int qg   = w & 3;           // q-group (16 rows)
    const int th   = w >> 2;          // t-half 0/1
    const int g    = lane >> 4;
    const int r    = lane & 15;

    const int ktw = tid & 7,  kdp = tid >> 3;    // K stage: t-octet, d-pair
    const int vwd = tid & 15, vtp = tid >> 4;    // V stage: d-word, t-pair

    // ---- Q B-fragments (scale baked in): col r <-> q = 16qg + r ----
    short8 qb[4];
    {
        const float* qrow = qry + ((size_t)bh * Qn + (16 * qg + r)) * Dn;
        #pragma unroll
        for (int m = 0; m < 4; ++m) {
            float4 f0 = *(const float4*)(qrow + m * 32 + 8 * g);
            float4 f1 = *(const float4*)(qrow + m * 32 + 8 * g + 4);
            f0.x *= SCALE_QK; f0.y *= SCALE_QK; f0.z *= SCALE_QK; f0.w *= SCALE_QK;
            f1.x *= SCALE_QK; f1.y *= SCALE_QK; f1.z *= SCALE_QK; f1.w *= SCALE_QK;
            qb[m] = pack8(f0, f1);
        }
    }

    // ---- permuted QK A-row mapping: lane r reads K rows t0p (s0) / t0p+4 (s1)
    // => S-values at lane(g,r) cover t = 32th + 8g + {0..7}  (in-lane PV B-frag!)
    const int t0p = 32 * th + 8 * (r >> 2) + (r & 3);
    const int t1p = t0p + 4;
    const int kkey0 = (((t0p & 7) ^ ((t0p >> 3) & 7)) << 4);
    const int kkey1 = (((t1p & 7) ^ ((t1p >> 3) & 7)) << 4);
    const int kb0 = (t0p << 8) + (g << 4);
    const int kb1 = (t1p << 8) + (g << 4);

    f32x4 o[8];
    #pragma unroll
    for (int nd = 0; nd < 8; ++nd) o[nd] = (f32x4){0.f, 0.f, 0.f, 0.f};
    float m_run = -INFINITY, l_run = 0.f;

    // ---- running prefetch pointers ----
    const int*   kpp  = kc  + (size_t)(2 * kdp) * (Tn / 8)  + ulo * 8 + ktw;
    const float* kscp = ksc + (size_t)(2 * kdp) * (Tn / 32) + ulo * 2 + (ktw >> 2);
    const float* kmmp = kmm + (size_t)(2 * kdp) * (Tn / 32) + ulo * 2 + (ktw >> 2);
    const int*   vcp  = vc  + ((size_t)ulo * 64 + 2 * vtp) * (Dn / 8)  + vwd;
    const float* vscp = vsc + ((size_t)ulo * 64 + 2 * vtp) * (Dn / 32) + (vwd >> 2);
    const float* vmmp = vmm + ((size_t)ulo * 64 + 2 * vtp) * (Dn / 32) + (vwd >> 2);

    int kc0, kc1, vc0, vc1;
    float ksc0, kmn0, ksc1, kmn1, vsc0, vmn0, vsc1, vmn1;
    auto pf = [&]() {
        kc0 = kpp[0]; kc1 = kpp[Tn / 8];
        ksc0 = kscp[0]; ksc1 = kscp[Tn / 32];
        kmn0 = kmmp[0]; kmn1 = kmmp[Tn / 32];
        vc0 = vcp[0]; vc1 = vcp[Dn / 8];
        vsc0 = vscp[0]; vsc1 = vscp[Dn / 32];
        vmn0 = vmmp[0]; vmn1 = vmmp[Dn / 32];
        kpp += 8; kscp += 2; kmmp += 2;
        vcp += 64 * (Dn / 8); vscp += 64 * (Dn / 32); vmmp += 64 * (Dn / 32);
    };
    pf();   // unit ulo (always quantized since ulo < 64 for NS<=8)

    const int q = 16 * qg + r;

    for (int u = ulo; u < uhi; ++u) {
        __syncthreads();   // B1: all consumers of previous tile done

        if (u < 64) {
            {   // K dequant: rows (d=2kdp, 2kdp+1), t = 8*ktw + j
                unsigned c0 = (unsigned)kc0, c1 = (unsigned)kc1;
                #pragma unroll
                for (int j = 0; j < 8; ++j) {
                    int t = 8 * ktw + j;
                    int key = (j ^ ktw) << 4;
                    *(unsigned*)(KpB + (((t << 8) + 4 * kdp) ^ key)) =
                        dq2(c0, c1, j, ksc0, kmn0, ksc1, kmn1);
                }
            }
            {   // V dequant: rows (t=2vtp, 2vtp+1), d = 8*vwd + i
                unsigned c0 = (unsigned)vc0, c1 = (unsigned)vc1;
                #pragma unroll
                for (int i = 0; i < 8; ++i) {
                    int d = 8 * vwd + i;
                    int key = (i ^ (vwd & 7)) << 4;
                    *(unsigned*)(VtB + (((d << 7) + 4 * vtp) ^ key)) =
                        dq2(c0, c1, i, vsc0, vmn0, vsc1, vmn1);
                }
            }
        } else {
            int rt = u - 64;
            {   // K residual fp32
                int t = tid & 63, dh = tid >> 6;
                const float* kr = kf + (size_t)(rt * 64 + t) * Dn + dh * 16;
                int key = ((t & 7) ^ ((t >> 3) & 7)) << 4;
                #pragma unroll
                for (int s = 0; s < 2; ++s) {
                    float4 f0 = *(const float4*)(kr + s * 8);
                    float4 f1 = *(const float4*)(kr + s * 8 + 4);
                    *(short8*)(KpB + (((t << 8) + dh * 32 + s * 16) ^ key)) = pack8(f0, f1);
                }
            }
            {   // V residual fp32 (transposed gather)
                int d = tid & 127, t4 = tid >> 7;
                const float* vr = vf + (size_t)(rt * 64 + t4 * 16) * Dn + d;
                int key = ((d & 7) ^ ((d >> 3) & 7)) << 4;
                #pragma unroll
                for (int s = 0; s < 2; ++s) {
                    float4 f0, f1;
                    f0.x = vr[(size_t)(s * 8 + 0) * Dn]; f0.y = vr[(size_t)(s * 8 + 1) * Dn];
                    f0.z = vr[(size_t)(s * 8 + 2) * Dn]; f0.w = vr[(size_t)(s * 8 + 3) * Dn];
                    f1.x = vr[(size_t)(s * 8 + 4) * Dn]; f1.y = vr[(size_t)(s * 8 + 5) * Dn];
                    f1.z = vr[(size_t)(s * 8 + 6) * Dn]; f1.w = vr[(size_t)(s * 8 + 7) * Dn];
                    *(short8*)(VtB + (((d << 7) + t4 * 32 + s * 16) ^ key)) = pack8(f0, f1);
                }
            }
        }
        __syncthreads();   // B2: tile staged

        // ---- issue next unit's global loads (drained at next B1) ----
        if (u + 1 < uhi && u + 1 < 64) pf();

        // ---- S^T = K Q^T (permuted rows): s0[reg] = S[t=32th+8g+reg][q], s1 = +4 ----
        f32x4 s0 = {0.f,0.f,0.f,0.f}, s1 = {0.f,0.f,0.f,0.f};
        {
            #pragma unroll
            for (int m = 0; m < 4; ++m) {
                short8 f0 = *(const short8*)(KpB + ((kb0 + (m << 6)) ^ kkey0));
                short8 f1 = *(const short8*)(KpB + ((kb1 + (m << 6)) ^ kkey1));
                s0 = __builtin_amdgcn_mfma_f32_16x16x32_bf16(f0, qb[m], s0, 0, 0, 0);
                s1 = __builtin_amdgcn_mfma_f32_16x16x32_bf16(f1, qb[m], s1, 0, 0, 0);
            }
        }

        // ---- causal mask (residual tiles only): s0 t = base+reg, s1 t = base+4+reg ----
        if (u >= 64) {
            int base = (u - 64) * 64 + 32 * th + 8 * g;
            #pragma unroll
            for (int reg = 0; reg < 4; ++reg) {
                if (base + reg     > 64 + q) s0[reg] = -1e30f;
                if (base + 4 + reg > 64 + q) s1[reg] = -1e30f;
            }
        }

        // ---- in-register online softmax (state per-lane, q = 16qg + r) ----
        {
            float mx = fmaxf(fmaxf(fmaxf(s0[0], s0[1]), fmaxf(s0[2], s0[3])),
                             fmaxf(fmaxf(s1[0], s1[1]), fmaxf(s1[2], s1[3])));
            mx = fmaxf(mx, __shfl_xor(mx, 16));
            mx = fmaxf(mx, __shfl_xor(mx, 32));
            bool defer = __all(mx <= m_run + DEFER_THR);   // T13: skip rescale
            float mnew = defer ? m_run : fmaxf(m_run, mx);
            float p0[4], p1[4];
            #pragma unroll
            for (int reg = 0; reg < 4; ++reg) {
                p0[reg] = __expf(s0[reg] - mnew);
                p1[reg] = __expf(s1[reg] - mnew);
            }
            float sum = ((p0[0] + p0[1]) + (p0[2] + p0[3]))
                      + ((p1[0] + p1[1]) + (p1[2] + p1[3]));
            sum += __shfl_xor(sum, 16);
            sum += __shfl_xor(sum, 32);
            if (!defer) {
                float alpha = __expf(m_run - mnew);
                l_run *= alpha;
                m_run = mnew;
                #pragma unroll
                for (int nd = 0; nd < 8; ++nd) {
                    #pragma unroll
                    for (int reg = 0; reg < 4; ++reg) o[nd][reg] *= alpha;
                }
            }
            l_run += sum;

            // ---- P fragment entirely in-lane: k = 8g + {0..7} = t 32th+8g+{0..7} ----
            short8 pfrag = pack8(make_float4(p0[0], p0[1], p0[2], p0[3]),
                                 make_float4(p1[0], p1[1], p1[2], p1[3]));

            // ---- O^T = V^T P^T : rows d = 16nd + (4g+reg), cols q = r (this lane's q!)
            #pragma unroll
            for (int nd = 0; nd < 8; ++nd) {
                int d = 16 * nd + r;
                int vkey = (((d & 7) ^ ((d >> 3) & 7)) << 4);
                short8 vb = *(const short8*)(VtB + (((d << 7) + 64 * th + 16 * g) ^ vkey));
                o[nd] = __builtin_amdgcn_mfma_f32_16x16x32_bf16(vb, pfrag, o[nd], 0, 0, 0);
            }
        }
    }

    // ---- epilogue: merge t-halves, transpose O^T -> [q][d], write out/partials ----
    __syncthreads();
    float* Osc = (float*)SMEM;                  // overlay: 32 KB f32
    float* mB  = (float*)(SMEM + 32768);        // [64]
    float* lB  = (float*)(SMEM + 32768 + 256);  // [64]
    if (th == 1) {
        #pragma unroll
        for (int nd = 0; nd < 8; ++nd) {
            #pragma unroll
            for (int reg = 0; reg < 4; ++reg)
                Osc[(16 * nd + 4 * g + reg) * 64 + q] = o[nd][reg];   // d-major
        }
        if (g == 0) { mB[q] = m_run; lB[q] = l_run; }
    }
    __syncthreads();
    if (th == 0) {
        float m2 = mB[q], l2 = lB[q];
        float M  = fmaxf(m_run, m2);
        float w1 = __expf(m_run - M), w2 = __expf(m2 - M);
        float lt = l_run * w1 + l2 * w2;
        float norm = (NS == 1) ? (1.0f / lt) : 1.0f;
        #pragma unroll
        for (int nd = 0; nd < 8; ++nd) {
            #pragma unroll
            for (int reg = 0; reg < 4; ++reg)
                o[nd][reg] = (o[nd][reg] * w1 +
                              Osc[(16 * nd + 4 * g + reg) * 64 + q] * w2) * norm;
        }
        if (NS > 1 && g == 0) {
            float* wsM = ws + (size_t)128 * NS * 8192;
            float* wsL = wsM + (size_t)128 * NS * 64;
            wsM[pb * 64 + q] = M;
            wsL[pb * 64 + q] = lt;
        }
    }
    __syncthreads();   // th0 reads of d-major Osc done before overwrite
    if (th == 0) {
        #pragma unroll
        for (int nd = 0; nd < 8; ++nd) {
            #pragma unroll
            for (int reg = 0; reg < 4; ++reg)
                Osc[q * 128 + 16 * nd + 4 * g + reg] = o[nd][reg];    // q-major
        }
    }
    __syncthreads();
    {   // coalesced copy [64][128] f32 -> destination
        float* dst = (NS == 1) ? (out + (size_t)bh * 8192) : (ws + (size_t)pb * 8192);
        int row = tid >> 3;          // 0..63
        int c   = tid & 7;
        #pragma unroll
        for (int cc = 0; cc < 4; ++cc) {
            int col4 = (c + 8 * cc) * 4;
            f32x4 v = *(const f32x4*)(Osc + row * 128 + col4);
            *(f32x4*)(dst + (size_t)row * 128 + col4) = v;
        }
    }
}

template<int NS>
__global__ __launch_bounds__(256, 1)
void kivi_combine(const float* __restrict__ ws, float* __restrict__ out)
{
    const int bh  = blockIdx.x;
    const int tid = threadIdx.x;
    const int q   = tid >> 2;
    const int dq  = (tid & 3) << 5;
    const float* wsO = ws;
    const float* wsM = ws + (size_t)128 * NS * 8192;
    const float* wsL = wsM + (size_t)128 * NS * 64;

    float mv[NS];
    float M = -INFINITY;
    #pragma unroll
    for (int sp = 0; sp < NS; ++sp) {
        mv[sp] = wsM[(bh * NS + sp) * 64 + q];
        M = fmaxf(M, mv[sp]);
    }
    float lt = 0.f;
    #pragma unroll
    for (int sp = 0; sp < NS; ++sp) {
        mv[sp] = __expf(mv[sp] - M);
        lt += wsL[(bh * NS + sp) * 64 + q] * mv[sp];
    }
    float inv = 1.0f / lt;
    float4 acc[8];
    #pragma unroll
    for (int i = 0; i < 8; ++i) acc[i] = make_float4(0.f, 0.f, 0.f, 0.f);
    #pragma unroll
    for (int sp = 0; sp < NS; ++sp) {
        const float* Op = wsO + ((size_t)(bh * NS + sp)) * 8192 + q * 128 + dq;
        float wgt = mv[sp];
        #pragma unroll
        for (int i = 0; i < 8; ++i) {
            float4 f = *(const float4*)(Op + 4 * i);
            acc[i].x += f.x * wgt; acc[i].y += f.y * wgt;
            acc[i].z += f.z * wgt; acc[i].w += f.w * wgt;
        }
    }
    float* op = out + (size_t)bh * 8192 + q * 128 + dq;
    #pragma unroll
    for (int i = 0; i < 8; ++i) {
        float4 f = make_float4(acc[i].x * inv, acc[i].y * inv, acc[i].z * inv, acc[i].w * inv);
        *(float4*)(op + 4 * i) = f;
    }
}

extern "C" void kernel_launch(void* const* d_in, const int* in_sizes, int n_in,
                              void* d_out, int out_size, void* d_ws, size_t ws_size,
                              hipStream_t stream) {
    const float* qry    = (const float*)d_in[0];
    const int*   kcode  = (const int*)  d_in[1];
    const float* kscale = (const float*)d_in[2];
    const float* kmn    = (const float*)d_in[3];
    const float* kfull  = (const float*)d_in[4];
    const int*   vcode  = (const int*)  d_in[5];
    const float* vscale = (const float*)d_in[6];
    const float* vmn    = (const float*)d_in[7];
    const float* vfull  = (const float*)d_in[8];
    float* out = (float*)d_out;
    float* ws  = (float*)d_ws;

    const size_t needPerNS = ((size_t)128 * 8192 + 2 * 128 * 64) * sizeof(float);
    if (ws_size >= 8 * needPerNS) {
        kivi_attn<8><<<dim3(Bn * Hn * 8), dim3(NTHREADS), 0, stream>>>(
            qry, kcode, kscale, kmn, kfull, vcode, vscale, vmn, vfull, out, ws);
        kivi_combine<8><<<dim3(Bn * Hn), dim3(256), 0, stream>>>(ws, out);
    } else if (ws_size >= 4 * needPerNS) {
        kivi_attn<4><<<dim3(Bn * Hn * 4), dim3(NTHREADS), 0, stream>>>(
            qry, kcode, kscale, kmn, kfull, vcode, vscale, vmn, vfull, out, ws);
        kivi_combine<4><<<dim3(Bn * Hn), dim3(256), 0, stream>>>(ws, out);
    } else if (ws_size >= 2 * needPerNS) {
        kivi_attn<2><<<dim3(Bn * Hn * 2), dim3(NTHREADS), 0, stream>>>(
            qry, kcode, kscale, kmn, kfull, vcode, vscale, vmn, vfull, out, ws);
        kivi_combine<2><<<dim3(Bn * Hn), dim3(256), 0, stream>>>(ws, out);
    } else {
        kivi_attn<1><<<dim3(Bn * Hn), dim3(NTHREADS), 0, stream>>>(
            qry, kcode, kscale, kmn, kfull, vcode, vscale, vmn, vfull, out, ws);
    }
}

// Round 9
// 113.480 us; speedup vs baseline: 2.9932x; 1.1700x over previous
//
#include <hip/hip_runtime.h>
#include <hip/hip_bf16.h>
#include <cmath>

#define Bn 4
#define Hn 32
#define Qn 64
#define Dn 128
#define Tn 4096
#define Rn 128
#define NTHREADS 512
#define SCALE_QK 0.08838834764831845f
#define NUNITS 66      // 64 quantized KV tiles of 64 + 2 residual tiles
#define DEFER_THR 8.0f

typedef __attribute__((ext_vector_type(8))) short short8;
typedef __attribute__((ext_vector_type(4))) float f32x4;

__device__ __forceinline__ unsigned pk2(float a, float b) {
    __hip_bfloat162 h = __float22bfloat162_rn(make_float2(a, b));
    unsigned u; __builtin_memcpy(&u, &h, 4); return u;
}
__device__ __forceinline__ short8 pack8(float4 f0, float4 f1) {
    unsigned u[4] = { pk2(f0.x,f0.y), pk2(f0.z,f0.w), pk2(f1.x,f1.y), pk2(f1.z,f1.w) };
    short8 s; __builtin_memcpy(&s, u, 16); return s;
}
__device__ __forceinline__ unsigned dq2(unsigned c0, unsigned c1, int j,
                                        float s0, float m0, float s1, float m1) {
    float v0 = (float)((c0 >> (4*j)) & 15u) * s0 + m0;
    float v1 = (float)((c1 >> (4*j)) & 15u) * s1 + m1;
    return pk2(v0, v1);
}

// LDS: double-buffered arena, 65536 B -> 2 blocks/CU.
//   buf c at SMEM + c*32768:  K [t=64][d=128] bf16 (256B rows), then V^T [d=128][t=64] (128B rows)
//   K XOR key: (((t>>3)&3) | ((t&1)<<2))<<4  -- full 8-quad spread for permuted QK reads
//   V XOR key: ((d&7)^((d>>3)&7))<<4
// ONE barrier per unit: stage(u+1)->buf(1-c) overlaps compute(u) on buf(c).
// epilogue overlay: SMEM[0..32768) = O^T scratch f32; +32768 mB[64]; +33024 lB[64]
template<int NS>
__global__ __launch_bounds__(NTHREADS, 4)
void kivi_attn(const float* __restrict__ qry,
               const int*   __restrict__ kcode,
               const float* __restrict__ kscale,
               const float* __restrict__ kmn,
               const float* __restrict__ kfull,
               const int*   __restrict__ vcode,
               const float* __restrict__ vscale,
               const float* __restrict__ vmn,
               const float* __restrict__ vfull,
               float* __restrict__ out,
               float* __restrict__ ws)
{
    __shared__ __align__(16) char SMEM[65536];

    const int tid = threadIdx.x;
    const int bh  = blockIdx.x / NS;
    const int sp  = blockIdx.x % NS;
    const int pb  = bh * NS + sp;
    const int ulo = (sp * NUNITS) / NS;
    const int uhi = ((sp + 1) * NUNITS) / NS;

    const int*   kc  = kcode  + (size_t)bh * (Dn * (Tn / 8));
    const float* ksc = kscale + (size_t)bh * (Dn * (Tn / 32));
    const float* kmm = kmn    + (size_t)bh * (Dn * (Tn / 32));
    const float* kf  = kfull  + (size_t)bh * (Rn * Dn);
    const int*   vc  = vcode  + (size_t)bh * (Tn * (Dn / 8));
    const float* vsc = vscale + (size_t)bh * (Tn * (Dn / 32));
    const float* vmm = vmn    + (size_t)bh * (Tn * (Dn / 32));
    const float* vf  = vfull  + (size_t)bh * (Rn * Dn);

    const int w    = tid >> 6;        // wave 0..7
    const int lane = tid & 63;
    const int qg   = w & 3;           // q-group (16 rows)
    const int th   = w >> 2;          // t-half 0/1
    const int g    = lane >> 4;
    const int r    = lane & 15;

    const int ktw = tid & 7,  kdp = tid >> 3;    // K stage: t-octet, d-pair
    const int vwd = tid & 15, vtp = tid >> 4;    // V stage: d-word, t-pair

    // ---- Q B-fragments (scale baked in): col r <-> q = 16qg + r ----
    short8 qb[4];
    {
        const float* qrow = qry + ((size_t)bh * Qn + (16 * qg + r)) * Dn;
        #pragma unroll
        for (int m = 0; m < 4; ++m) {
            float4 f0 = *(const float4*)(qrow + m * 32 + 8 * g);
            float4 f1 = *(const float4*)(qrow + m * 32 + 8 * g + 4);
            f0.x *= SCALE_QK; f0.y *= SCALE_QK; f0.z *= SCALE_QK; f0.w *= SCALE_QK;
            f1.x *= SCALE_QK; f1.y *= SCALE_QK; f1.z *= SCALE_QK; f1.w *= SCALE_QK;
            qb[m] = pack8(f0, f1);
        }
    }

    // ---- permuted QK A-row mapping: A-row rho holds K[t = 32th + 8(rho>>2) + (rho&3)]
    // => lane(g,r)'s s0/s1 regs cover t = 32th + 8g + {0..7}  (in-lane PV B-frag)
    const int t0p  = 32 * th + 8 * (r >> 2) + (r & 3);
    const int kkey = (((r >> 2) | ((r & 1) << 2)) << 4);   // key(t0p) == key(t0p+4)
    const int kb0  = (t0p << 8) + (g << 4);
    const int kb1  = kb0 + (4 << 8);

    f32x4 o[8];
    #pragma unroll
    for (int nd = 0; nd < 8; ++nd) o[nd] = (f32x4){0.f, 0.f, 0.f, 0.f};
    float m_run = -INFINITY, l_run = 0.f;

    // ---- running prefetch pointers ----
    const int*   kpp  = kc  + (size_t)(2 * kdp) * (Tn / 8)  + ulo * 8 + ktw;
    const float* kscp = ksc + (size_t)(2 * kdp) * (Tn / 32) + ulo * 2 + (ktw >> 2);
    const float* kmmp = kmm + (size_t)(2 * kdp) * (Tn / 32) + ulo * 2 + (ktw >> 2);
    const int*   vcp  = vc  + ((size_t)ulo * 64 + 2 * vtp) * (Dn / 8)  + vwd;
    const float* vscp = vsc + ((size_t)ulo * 64 + 2 * vtp) * (Dn / 32) + (vwd >> 2);
    const float* vmmp = vmm + ((size_t)ulo * 64 + 2 * vtp) * (Dn / 32) + (vwd >> 2);

    int kc0, kc1, vc0, vc1;
    float ksc0, kmn0, ksc1, kmn1, vsc0, vmn0, vsc1, vmn1;
    auto pf = [&]() {
        kc0 = kpp[0]; kc1 = kpp[Tn / 8];
        ksc0 = kscp[0]; ksc1 = kscp[Tn / 32];
        kmn0 = kmmp[0]; kmn1 = kmmp[Tn / 32];
        vc0 = vcp[0]; vc1 = vcp[Dn / 8];
        vsc0 = vscp[0]; vsc1 = vscp[Dn / 32];
        vmn0 = vmmp[0]; vmn1 = vmmp[Dn / 32];
        kpp += 8; kscp += 2; kmmp += 2;
        vcp += 64 * (Dn / 8); vscp += 64 * (Dn / 32); vmmp += 64 * (Dn / 32);
    };

    auto stage_quant = [&](char* Kb, char* Vb) {
        unsigned c0 = (unsigned)kc0, c1 = (unsigned)kc1;
        #pragma unroll
        for (int j = 0; j < 8; ++j) {
            int t = 8 * ktw + j;
            int key = (((t >> 3) & 3) | ((t & 1) << 2)) << 4;
            *(unsigned*)(Kb + (((t << 8) + 4 * kdp) ^ key)) =
                dq2(c0, c1, j, ksc0, kmn0, ksc1, kmn1);
        }
        unsigned e0 = (unsigned)vc0, e1 = (unsigned)vc1;
        #pragma unroll
        for (int i = 0; i < 8; ++i) {
            int d = 8 * vwd + i;
            int key = (i ^ (vwd & 7)) << 4;
            *(unsigned*)(Vb + (((d << 7) + 4 * vtp) ^ key)) =
                dq2(e0, e1, i, vsc0, vmn0, vsc1, vmn1);
        }
    };
    auto stage_resid = [&](int rt, char* Kb, char* Vb) {
        {   // K residual fp32 (new K key)
            int t = tid & 63, dh = tid >> 6;
            const float* kr = kf + (size_t)(rt * 64 + t) * Dn + dh * 16;
            int key = (((t >> 3) & 3) | ((t & 1) << 2)) << 4;
            #pragma unroll
            for (int s = 0; s < 2; ++s) {
                float4 f0 = *(const float4*)(kr + s * 8);
                float4 f1 = *(const float4*)(kr + s * 8 + 4);
                *(short8*)(Kb + (((t << 8) + dh * 32 + s * 16) ^ key)) = pack8(f0, f1);
            }
        }
        {   // V residual fp32 (transposed gather)
            int d = tid & 127, t4 = tid >> 7;
            const float* vr = vf + (size_t)(rt * 64 + t4 * 16) * Dn + d;
            int key = ((d & 7) ^ ((d >> 3) & 7)) << 4;
            #pragma unroll
            for (int s = 0; s < 2; ++s) {
                float4 f0, f1;
                f0.x = vr[(size_t)(s * 8 + 0) * Dn]; f0.y = vr[(size_t)(s * 8 + 1) * Dn];
                f0.z = vr[(size_t)(s * 8 + 2) * Dn]; f0.w = vr[(size_t)(s * 8 + 3) * Dn];
                f1.x = vr[(size_t)(s * 8 + 4) * Dn]; f1.y = vr[(size_t)(s * 8 + 5) * Dn];
                f1.z = vr[(size_t)(s * 8 + 6) * Dn]; f1.w = vr[(size_t)(s * 8 + 7) * Dn];
                *(short8*)(Vb + (((d << 7) + t4 * 32 + s * 16) ^ key)) = pack8(f0, f1);
            }
        }
    };

    const int q = 16 * qg + r;

    // ---- prologue: stage unit ulo into buf0 (ulo < 64 always for NS<=4) ----
    pf();                                   // regs for ulo
    stage_quant(SMEM, SMEM + 16384);
    if (ulo + 1 < uhi && ulo + 1 < 64) pf();   // regs for ulo+1
    __syncthreads();

    for (int u = ulo; u < uhi; ++u) {
        const int cur = (u - ulo) & 1;
        char* Kc = SMEM + (cur << 15);
        char* Vc = Kc + 16384;

        // ---- stage next unit into the other buffer (overlaps compute below) ----
        if (u + 1 < uhi) {
            char* Kn = SMEM + ((cur ^ 1) << 15);
            char* Vn = Kn + 16384;
            if (u + 1 < 64) {
                stage_quant(Kn, Vn);
                if (u + 2 < uhi && u + 2 < 64) pf();   // regs for u+2
            } else {
                stage_resid(u + 1 - 64, Kn, Vn);
            }
        }

        // ---- S^T = K Q^T (permuted rows): s0[reg] -> t = 32th+8g+reg, s1 -> +4 ----
        f32x4 s0 = {0.f,0.f,0.f,0.f}, s1 = {0.f,0.f,0.f,0.f};
        #pragma unroll
        for (int m = 0; m < 4; ++m) {
            short8 f0 = *(const short8*)(Kc + ((kb0 + (m << 6)) ^ kkey));
            short8 f1 = *(const short8*)(Kc + ((kb1 + (m << 6)) ^ kkey));
            s0 = __builtin_amdgcn_mfma_f32_16x16x32_bf16(f0, qb[m], s0, 0, 0, 0);
            s1 = __builtin_amdgcn_mfma_f32_16x16x32_bf16(f1, qb[m], s1, 0, 0, 0);
        }

        // ---- causal mask (residual tiles only) ----
        if (u >= 64) {
            int base = (u - 64) * 64 + 32 * th + 8 * g;
            #pragma unroll
            for (int reg = 0; reg < 4; ++reg) {
                if (base + reg     > 64 + q) s0[reg] = -1e30f;
                if (base + 4 + reg > 64 + q) s1[reg] = -1e30f;
            }
        }

        // ---- in-register online softmax (per-lane state, q = 16qg + r) ----
        {
            float mx = fmaxf(fmaxf(fmaxf(s0[0], s0[1]), fmaxf(s0[2], s0[3])),
                             fmaxf(fmaxf(s1[0], s1[1]), fmaxf(s1[2], s1[3])));
            mx = fmaxf(mx, __shfl_xor(mx, 16));
            mx = fmaxf(mx, __shfl_xor(mx, 32));
            bool defer = __all(mx <= m_run + DEFER_THR);   // T13
            float mnew = defer ? m_run : fmaxf(m_run, mx);
            float p0[4], p1[4];
            #pragma unroll
            for (int reg = 0; reg < 4; ++reg) {
                p0[reg] = __expf(s0[reg] - mnew);
                p1[reg] = __expf(s1[reg] - mnew);
            }
            float sum = ((p0[0] + p0[1]) + (p0[2] + p0[3]))
                      + ((p1[0] + p1[1]) + (p1[2] + p1[3]));
            sum += __shfl_xor(sum, 16);
            sum += __shfl_xor(sum, 32);
            if (!defer) {
                float alpha = __expf(m_run - mnew);
                l_run *= alpha;
                m_run = mnew;
                #pragma unroll
                for (int nd = 0; nd < 8; ++nd) {
                    #pragma unroll
                    for (int reg = 0; reg < 4; ++reg) o[nd][reg] *= alpha;
                }
            }
            l_run += sum;

            // ---- P fragment in-lane: k-slot j <-> t = 32th+8g+j ----
            short8 pfrag = pack8(make_float4(p0[0], p0[1], p0[2], p0[3]),
                                 make_float4(p1[0], p1[1], p1[2], p1[3]));

            // ---- O^T = V^T P^T ----
            #pragma unroll
            for (int nd = 0; nd < 8; ++nd) {
                int d = 16 * nd + r;
                int vkey = ((d & 7) ^ ((d >> 3) & 7)) << 4;
                short8 vb = *(const short8*)(Vc + (((d << 7) + 64 * th + 16 * g) ^ vkey));
                o[nd] = __builtin_amdgcn_mfma_f32_16x16x32_bf16(vb, pfrag, o[nd], 0, 0, 0);
            }
        }
        __syncthreads();   // buf(cur) consumed; buf(cur^1) staged
    }

    // ---- epilogue: merge t-halves, transpose O^T -> [q][d], write out/partials ----
    float* Osc = (float*)SMEM;                  // overlay 32 KB
    float* mB  = (float*)(SMEM + 32768);
    float* lB  = (float*)(SMEM + 32768 + 256);
    if (th == 1) {
        #pragma unroll
        for (int nd = 0; nd < 8; ++nd) {
            #pragma unroll
            for (int reg = 0; reg < 4; ++reg)
                Osc[(16 * nd + 4 * g + reg) * 64 + q] = o[nd][reg];   // d-major
        }
        if (g == 0) { mB[q] = m_run; lB[q] = l_run; }
    }
    __syncthreads();
    if (th == 0) {
        float m2 = mB[q], l2 = lB[q];
        float M  = fmaxf(m_run, m2);
        float w1 = __expf(m_run - M), w2 = __expf(m2 - M);
        float lt = l_run * w1 + l2 * w2;
        float norm = (NS == 1) ? (1.0f / lt) : 1.0f;
        #pragma unroll
        for (int nd = 0; nd < 8; ++nd) {
            #pragma unroll
            for (int reg = 0; reg < 4; ++reg)
                o[nd][reg] = (o[nd][reg] * w1 +
                              Osc[(16 * nd + 4 * g + reg) * 64 + q] * w2) * norm;
        }
        if (NS > 1 && g == 0) {
            float* wsM = ws + (size_t)128 * NS * 8192;
            float* wsL = wsM + (size_t)128 * NS * 64;
            wsM[pb * 64 + q] = M;
            wsL[pb * 64 + q] = lt;
        }
    }
    __syncthreads();   // th0 reads of d-major Osc done before overwrite
    if (th == 0) {
        #pragma unroll
        for (int nd = 0; nd < 8; ++nd) {
            #pragma unroll
            for (int reg = 0; reg < 4; ++reg)
                Osc[q * 128 + 16 * nd + 4 * g + reg] = o[nd][reg];    // q-major
        }
    }
    __syncthreads();
    {   // coalesced copy [64][128] f32 -> destination
        float* dst = (NS == 1) ? (out + (size_t)bh * 8192) : (ws + (size_t)pb * 8192);
        int row = tid >> 3;
        int c   = tid & 7;
        #pragma unroll
        for (int cc = 0; cc < 4; ++cc) {
            int col4 = (c + 8 * cc) * 4;
            f32x4 v = *(const f32x4*)(Osc + row * 128 + col4);
            *(f32x4*)(dst + (size_t)row * 128 + col4) = v;
        }
    }
}

template<int NS>
__global__ __launch_bounds__(256, 1)
void kivi_combine(const float* __restrict__ ws, float* __restrict__ out)
{
    const int bh  = blockIdx.x;
    const int tid = threadIdx.x;
    const int q   = tid >> 2;
    const int dq  = (tid & 3) << 5;
    const float* wsO = ws;
    const float* wsM = ws + (size_t)128 * NS * 8192;
    const float* wsL = wsM + (size_t)128 * NS * 64;

    float mv[NS];
    float M = -INFINITY;
    #pragma unroll
    for (int sp = 0; sp < NS; ++sp) {
        mv[sp] = wsM[(bh * NS + sp) * 64 + q];
        M = fmaxf(M, mv[sp]);
    }
    float lt = 0.f;
    #pragma unroll
    for (int sp = 0; sp < NS; ++sp) {
        mv[sp] = __expf(mv[sp] - M);
        lt += wsL[(bh * NS + sp) * 64 + q] * mv[sp];
    }
    float inv = 1.0f / lt;
    float4 acc[8];
    #pragma unroll
    for (int i = 0; i < 8; ++i) acc[i] = make_float4(0.f, 0.f, 0.f, 0.f);
    #pragma unroll
    for (int sp = 0; sp < NS; ++sp) {
        const float* Op = wsO + ((size_t)(bh * NS + sp)) * 8192 + q * 128 + dq;
        float wgt = mv[sp];
        #pragma unroll
        for (int i = 0; i < 8; ++i) {
            float4 f = *(const float4*)(Op + 4 * i);
            acc[i].x += f.x * wgt; acc[i].y += f.y * wgt;
            acc[i].z += f.z * wgt; acc[i].w += f.w * wgt;
        }
    }
    float* op = out + (size_t)bh * 8192 + q * 128 + dq;
    #pragma unroll
    for (int i = 0; i < 8; ++i) {
        float4 f = make_float4(acc[i].x * inv, acc[i].y * inv, acc[i].z * inv, acc[i].w * inv);
        *(float4*)(op + 4 * i) = f;
    }
}

extern "C" void kernel_launch(void* const* d_in, const int* in_sizes, int n_in,
                              void* d_out, int out_size, void* d_ws, size_t ws_size,
                              hipStream_t stream) {
    const float* qry    = (const float*)d_in[0];
    const int*   kcode  = (const int*)  d_in[1];
    const float* kscale = (const float*)d_in[2];
    const float* kmn    = (const float*)d_in[3];
    const float* kfull  = (const float*)d_in[4];
    const int*   vcode  = (const int*)  d_in[5];
    const float* vscale = (const float*)d_in[6];
    const float* vmn    = (const float*)d_in[7];
    const float* vfull  = (const float*)d_in[8];
    float* out = (float*)d_out;
    float* ws  = (float*)d_ws;

    const size_t needPerNS = ((size_t)128 * 8192 + 2 * 128 * 64) * sizeof(float);
    if (ws_size >= 4 * needPerNS) {
        kivi_attn<4><<<dim3(Bn * Hn * 4), dim3(NTHREADS), 0, stream>>>(
            qry, kcode, kscale, kmn, kfull, vcode, vscale, vmn, vfull, out, ws);
        kivi_combine<4><<<dim3(Bn * Hn), dim3(256), 0, stream>>>(ws, out);
    } else if (ws_size >= 2 * needPerNS) {
        kivi_attn<2><<<dim3(Bn * Hn * 2), dim3(NTHREADS), 0, stream>>>(
            qry, kcode, kscale, kmn, kfull, vcode, vscale, vmn, vfull, out, ws);
        kivi_combine<2><<<dim3(Bn * Hn), dim3(256), 0, stream>>>(ws, out);
    } else {
        kivi_attn<1><<<dim3(Bn * Hn), dim3(NTHREADS), 0, stream>>>(
            qry, kcode, kscale, kmn, kfull, vcode, vscale, vmn, vfull, out, ws);
    }
}